// Round 6
// baseline (258.949 us; speedup 1.0000x reference)
//
#include <hip/hip_runtime.h>

// DAGConstraintLayer: out[b,i] = sigmoid(min over root-to-i chain of x[b,i]).
// R8 post-mortem: the no-LDS register-streaming control (bperm path-min) hit
// 86us @ 2.37 TB/s — same as LDS-barrier (83), LDS-pipelined (88), flat (83).
// Four independent schedules converge: schedule/LDS/width are not the
// variable. What they share is the HBM byte count: FETCH 66MB + WRITE 133MB.
// FETCH = exactly half the 133MB input: input+output = 266MB > 256MB LLC, so
// output write-allocations evict input lines (~50% steady-state hit rate).
// Output is written once and never read -> caching it is pure pollution.
// R9 = R8 + __builtin_nontemporal_store on all outputs (global_store ... nt,
// no LLC allocation): input becomes fully LLC-resident across dispatches,
// HBM traffic drops to ~writes-only (~133MB). Single-variable change.
//
// Design recap (R8): one WAVE = one ROW (127 floats); lane l holds node l
// (slot A) and node 64+l (slot B, lanes 0..62, all depth-6 leaves). Ancestor
// path-min via pointer-doubling ds_bpermute jumps 1,2,4 (anc_k(l) =
// ((l+1)>>k)-1, clamped to 0 = root, always sound); slot B takes one more
// bpermute from its (already final) parent lane (63+l)>>1. Coalesced dword
// register streams, 4-slot rotation, prefetch distance 2. No LDS, no
// barriers, no inline-asm waits.

#define NODES 127
#define BLOCK 256
#define WPB   (BLOCK / 64)           // 4 waves per block
#define TPW   32                     // rows per wave

__device__ __forceinline__ float sigf(float v) {
    return 1.0f / (1.0f + __expf(-v));
}

__device__ __forceinline__ float bperm_min(float p, int idx) {
    return fminf(p, __int_as_float(
        __builtin_amdgcn_ds_bpermute(idx, __float_as_int(p))));
}

__global__ __launch_bounds__(BLOCK, 8) void dag_kernel(const float* __restrict__ x,
                                                       float* __restrict__ out) {
    const int t  = threadIdx.x;
    const int wv = t >> 6;
    const int l  = t & 63;
    const long long W    = (long long)blockIdx.x * WPB + wv;  // global wave id
    const long long row0 = W * TPW;                           // first row

    // Loop-invariant per-lane bpermute byte-indices (pointer-doubling jumps).
    const int i1 = ((l + 1) >> 1) - 1;
    const int i2 = ((l + 1) >> 2) - 1;
    const int i4 = ((l + 1) >> 4) - 1;
    const int s1 = 4 * (i1 < 0 ? 0 : i1);
    const int s2 = 4 * (i2 < 0 ? 0 : i2);
    const int s4 = 4 * (i4 < 0 ? 0 : i4);
    const int sB = 4 * ((63 + l) >> 1);   // parent lane of node 64+l (depth-5)
    const int lb = (l < 63) ? l : 62;     // clamp lane-63 slot-B load (dummy;
                                          // avoids 4B OOB read on final row)

    const float* __restrict__ xp = x   + row0 * NODES;
    float*       __restrict__ op = out + row0 * NODES;

    float A[4], B[4];                     // rotation slots (static idx only)

#define LOADROW(j, slot) do {                                   \
        const float* rp_ = xp + (size_t)(j) * NODES;            \
        A[slot] = rp_[l];                                       \
        B[slot] = rp_[64 + lb];                                 \
    } while (0)

    LOADROW(0, 0);
    LOADROW(1, 1);

    #pragma unroll
    for (int j = 0; j < TPW; ++j) {
        const int cs = j & 3;
        if (j + 2 < TPW) LOADROW(j + 2, (j + 2) & 3);   // prefetch distance 2

        // ---- slot A: min over ancestor chain via jumps 1,2,4 ----
        float p = A[cs];
        p = bperm_min(p, s1);
        p = bperm_min(p, s2);
        p = bperm_min(p, s4);
        // ---- slot B: depth-6 leaves; parent path-min is already final ----
        float q = fminf(B[cs], __int_as_float(
            __builtin_amdgcn_ds_bpermute(sB, __float_as_int(p))));

        // Non-temporal stores: output is write-once/never-read; keep it out
        // of L2/LLC so the input stays LLC-resident (the R9 variable).
        float* rp = op + (size_t)j * NODES;
        __builtin_nontemporal_store(sigf(p), rp + l);       // nodes 0..63
        if (l < 63)
            __builtin_nontemporal_store(sigf(q), rp + 64 + l); // nodes 64..126
    }
#undef LOADROW
}

extern "C" void kernel_launch(void* const* d_in, const int* in_sizes, int n_in,
                              void* d_out, int out_size, void* d_ws, size_t ws_size,
                              hipStream_t stream) {
    const float* x = (const float*)d_in[0];
    float* out = (float*)d_out;
    int rows  = in_sizes[0] / NODES;      // 262144
    int waves = rows / TPW;               // 8192
    int grid  = waves / WPB;              // 2048 = 8 blocks/CU exactly
    dag_kernel<<<grid, BLOCK, 0, stream>>>(x, out);
}

// Round 7
// 245.339 us; speedup vs baseline: 1.0555x; 1.0555x over previous
//
#include <hip/hip_runtime.h>

// DAGConstraintLayer: out[b,i] = sigmoid(min over root-to-i chain of x[b,i]).
// R9 post-mortem: nontemporal stores REGRESSED (86->105us): FETCH unchanged
// (input-eviction theory dead) and WRITE amplified 130->149MB (nt dword
// stores defeat line merging at 508B row boundaries -> partial-line
// writeouts). Reverted. Standing evidence: 4 schedules (LDS-barrier,
// LDS-pipelined, flat, register-bpermute) all ~83-87us @ ~2.4 TB/s, every
// pipe <35%. Shared structural property vs the 6.3 TB/s copy ubench:
// PRIVATE-CHUNK ownership — each wave walks its own contiguous 16KB, so the
// controllers see ~8192 scattered streams (DRAM row/turnaround thrash).
// R10 = R8 with ONE change: interleaved ownership. At step j, wave W does
// row j*NWAVES + W -> the whole machine touches one contiguous ~4.2MB window
// sweeping the buffer (copy-like), instead of 8192 streams 16KB apart.
//
// Design recap (R8): one WAVE = one ROW (127 floats); lane l holds node l
// (slot A) and node 64+l (slot B, lanes 0..62, all depth-6 leaves). Ancestor
// path-min via pointer-doubling ds_bpermute jumps 1,2,4 (anc_k(l) =
// ((l+1)>>k)-1, clamped to 0 = root, always sound); slot B takes one more
// bpermute from its (already final) parent lane (63+l)>>1. Monotone sigmoid
// commutes with min. Coalesced dword register streams, 4-slot rotation,
// prefetch distance 2. No LDS, no barriers, no inline-asm waits.

#define NODES 127
#define BLOCK 256
#define WPB   (BLOCK / 64)           // 4 waves per block
#define TPW   32                     // rows per wave

__device__ __forceinline__ float sigf(float v) {
    return 1.0f / (1.0f + __expf(-v));
}

__device__ __forceinline__ float bperm_min(float p, int idx) {
    return fminf(p, __int_as_float(
        __builtin_amdgcn_ds_bpermute(idx, __float_as_int(p))));
}

__global__ __launch_bounds__(BLOCK, 8) void dag_kernel(const float* __restrict__ x,
                                                       float* __restrict__ out) {
    const int t  = threadIdx.x;
    const int wv = t >> 6;
    const int l  = t & 63;
    const int W  = blockIdx.x * WPB + wv;            // global wave id
    const int NW = gridDim.x * WPB;                  // total waves (8192)
    const size_t rstride = (size_t)NW * NODES;       // floats between steps

    // Loop-invariant per-lane bpermute byte-indices (pointer-doubling jumps).
    const int i1 = ((l + 1) >> 1) - 1;
    const int i2 = ((l + 1) >> 2) - 1;
    const int i4 = ((l + 1) >> 4) - 1;
    const int s1 = 4 * (i1 < 0 ? 0 : i1);
    const int s2 = 4 * (i2 < 0 ? 0 : i2);
    const int s4 = 4 * (i4 < 0 ? 0 : i4);
    const int sB = 4 * ((63 + l) >> 1);   // parent lane of node 64+l (depth-5)
    const int lb = (l < 63) ? l : 62;     // clamp lane-63 slot-B load (dummy;
                                          // avoids 4B OOB read on final row)

    // Interleaved ownership: row(j) = j*NW + W.
    const float* __restrict__ xp = x   + (size_t)W * NODES;
    float*       __restrict__ op = out + (size_t)W * NODES;

    float A[4], B[4];                     // rotation slots (static idx only)

#define LOADROW(j, slot) do {                                   \
        const float* rp_ = xp + (size_t)(j) * rstride;          \
        A[slot] = rp_[l];                                       \
        B[slot] = rp_[64 + lb];                                 \
    } while (0)

    LOADROW(0, 0);
    LOADROW(1, 1);

    #pragma unroll
    for (int j = 0; j < TPW; ++j) {
        const int cs = j & 3;
        if (j + 2 < TPW) LOADROW(j + 2, (j + 2) & 3);   // prefetch distance 2

        // ---- slot A: min over ancestor chain via jumps 1,2,4 ----
        float p = A[cs];
        p = bperm_min(p, s1);
        p = bperm_min(p, s2);
        p = bperm_min(p, s4);
        // ---- slot B: depth-6 leaves; parent path-min is already final ----
        float q = fminf(B[cs], __int_as_float(
            __builtin_amdgcn_ds_bpermute(sB, __float_as_int(p))));

        float* rp = op + (size_t)j * rstride;
        rp[l] = sigf(p);                  // nodes 0..63, all 64 lanes
        if (l < 63) rp[64 + l] = sigf(q); // nodes 64..126
    }
#undef LOADROW
}

extern "C" void kernel_launch(void* const* d_in, const int* in_sizes, int n_in,
                              void* d_out, int out_size, void* d_ws, size_t ws_size,
                              hipStream_t stream) {
    const float* x = (const float*)d_in[0];
    float* out = (float*)d_out;
    int rows  = in_sizes[0] / NODES;      // 262144
    int waves = rows / TPW;               // 8192
    int grid  = waves / WPB;              // 2048 = 8 blocks/CU exactly
    dag_kernel<<<grid, BLOCK, 0, stream>>>(x, out);
}